// Round 13
// baseline (260.418 us; speedup 1.0000x reference)
//
#include <hip/hip_runtime.h>
#include <hip/hip_bf16.h>
#include <hip/hip_fp8.h>

#define DIN   128
#define DH    128
#define DOUTC 64
#define BN_EPS 1e-5f

typedef __attribute__((ext_vector_type(8))) short bf16x8;
typedef __attribute__((ext_vector_type(4))) float f32x4;
typedef __attribute__((ext_vector_type(2))) float f32x2;

#ifndef __has_builtin
#define __has_builtin(x) 0
#endif
#if __has_builtin(__builtin_amdgcn_cvt_pk_f32_fp8) && __has_builtin(__builtin_amdgcn_cvt_pk_fp8_f32)
#define HW_FP8 1
#else
#define HW_FP8 0
#endif

__device__ inline unsigned short f2bf(float f) {
    __hip_bfloat16 b = __float2bfloat16(f);
    return *reinterpret_cast<unsigned short*>(&b);
}
__device__ inline float bf2f(unsigned short u) {
    return __uint_as_float(((unsigned int)u) << 16);
}
__device__ inline void fp8x4_to_f32(unsigned int w, float* o) {
#if HW_FP8
    f32x2 lo = __builtin_amdgcn_cvt_pk_f32_fp8((int)w, false);
    f32x2 hi = __builtin_amdgcn_cvt_pk_f32_fp8((int)w, true);
    o[0] = lo.x; o[1] = lo.y; o[2] = hi.x; o[3] = hi.y;
#else
    #pragma unroll
    for (int c = 0; c < 4; ++c) {
        __hip_fp8_e4m3 q; q.__x = (__hip_fp8_storage_t)((w >> (8 * c)) & 0xFF);
        o[c] = (float)q;
    }
#endif
}
__device__ inline unsigned int f32x4_to_fp8(float a, float b, float c, float d) {
#if HW_FP8
    int p = __builtin_amdgcn_cvt_pk_fp8_f32(a, b, 0, false);
    p = __builtin_amdgcn_cvt_pk_fp8_f32(c, d, p, true);
    return (unsigned int)p;
#else
    __hip_fp8_e4m3 qa(a), qb(b), qc(c), qd(d);
    return (unsigned int)qa.__x | ((unsigned int)qb.__x << 8) |
           ((unsigned int)qc.__x << 16) | ((unsigned int)qd.__x << 24);
#endif
}

// ---------------------------------------------------------------------------
// Exclusive prefix scan over 256 LDS ints (all 256 threads must call).
// ---------------------------------------------------------------------------
__device__ inline void block_excl_scan_256(const int* __restrict__ arr,
                                           int* __restrict__ excl,
                                           int* __restrict__ wsum, int tid)
{
    int lane = tid & 63, w = tid >> 6;
    int v = arr[tid];
    int inc = v;
    #pragma unroll
    for (int off = 1; off < 64; off <<= 1) {
        int t = __shfl_up(inc, off, 64);
        if (lane >= off) inc += t;
    }
    if (lane == 63) wsum[w] = inc;
    __syncthreads();
    if (tid == 0) {
        int s = 0;
        #pragma unroll
        for (int i = 0; i < 4; ++i) { int t = wsum[i]; wsum[i] = s; s += t; }
    }
    __syncthreads();
    excl[tid] = inc - v + wsum[w];
    __syncthreads();
}

// ---------------------------------------------------------------------------
// prep_kernel — three independent block ranges:
//   [0, cvtB)              : x -> xq (fp8 e4m3)
//   [cvtB, cvtB+192)       : pack Wl1 / Wr1 / [Wl2|Wr2] into MFMA B-frag order
//   [cvtB+192, ...)        : bin_coarse — counting-sort pass A (dst>>8)
// ---------------------------------------------------------------------------
__global__ __launch_bounds__(256) void prep_kernel(
    const float* __restrict__ x, unsigned char* __restrict__ xq,
    const float* __restrict__ Wl1, const float* __restrict__ Wr1,
    const float* __restrict__ Wl2, const float* __restrict__ Wr2,
    unsigned short* __restrict__ W1p, unsigned short* __restrict__ W2p,
    const int* __restrict__ ei, int* __restrict__ cursor,
    unsigned int* __restrict__ coarse,
    int total8, int cvtB, int E, int nb, int cap)
{
    __shared__ int hist[256], lstart[256], gbase[256], wsum[4];
    __shared__ unsigned int staged[4096];
    const int b = blockIdx.x;
    const int tid = threadIdx.x;

    if (b < cvtB) {
        int i = b * 256 + tid;
        if (i >= total8) return;
        float4 a = ((const float4*)x)[2 * i];
        float4 c = ((const float4*)x)[2 * i + 1];
        uint2 pk;
        pk.x = f32x4_to_fp8(a.x, a.y, a.z, a.w);
        pk.y = f32x4_to_fp8(c.x, c.y, c.z, c.w);
        *(uint2*)(xq + (size_t)i * 8) = pk;
        return;
    }
    if (b < cvtB + 192) {
        int region = (b - cvtB) >> 6;
        int idx = ((b - cvtB) & 63) * 256 + tid;   // 0..16383
        int k = idx >> 7, c = idx & 127;
        int d = ((k >> 5) * 8 + (c >> 4)) * 512 + ((k >> 3) & 3) * 128 + (c & 15) * 8 + (k & 7);
        if (region == 0)      W1p[d] = f2bf(Wl1[idx]);
        else if (region == 1) W1p[128 * 128 + d] = f2bf(Wr1[idx]);
        else {
            float v = (c < 64) ? Wl2[k * 64 + c] : Wr2[k * 64 + (c - 64)];
            W2p[d] = f2bf(v);
        }
        return;
    }

    // ---- bin_coarse ----
    const int chunkBase = (b - cvtB - 192) * 4096;
    hist[tid] = 0;
    __syncthreads();

    unsigned int rec[16]; int pos[16]; int bb[16];
    #pragma unroll
    for (int i = 0; i < 16; ++i) {
        int e = chunkBase + i * 256 + tid;
        if (e < E) {
            int s = ei[e], d = ei[E + e];
            rec[i] = ((unsigned int)d << 16) | (unsigned int)s;
            bb[i]  = d >> 8;
            pos[i] = atomicAdd(&hist[bb[i]], 1);
        } else bb[i] = -1;
    }
    __syncthreads();

    block_excl_scan_256(hist, lstart, wsum, tid);

    if (tid < nb) {
        int c = hist[tid];
        gbase[tid] = c ? atomicAdd(&cursor[tid], c) : 0;
    }
    __syncthreads();

    #pragma unroll
    for (int i = 0; i < 16; ++i)
        if (bb[i] >= 0) staged[lstart[bb[i]] + pos[i]] = rec[i];
    __syncthreads();

    int total = min(4096, E - chunkBase);
    for (int i = tid; i < total; i += 256) {
        unsigned int r = staged[i];
        int bk  = (int)(r >> 24);
        int gp  = gbase[bk] + (i - lstart[bk]);
        if (gp < cap) coarse[(size_t)bk * cap + gp] = r;
    }
}

// ---------------------------------------------------------------------------
// Counting sort pass B: one block per coarse bucket; scatter src (ushort)
// into bucket-owned window; emit deg / row_start.
// ---------------------------------------------------------------------------
__global__ __launch_bounds__(256) void bin_fine(
    const int* __restrict__ cursor, const unsigned int* __restrict__ coarse,
    unsigned short* __restrict__ sorted, int* __restrict__ deg,
    int* __restrict__ row_start, int n, int cap)
{
    __shared__ int hist[256], pstart[256], cur2[256], wsum[4];
    const int b = blockIdx.x, tid = threadIdx.x;
    const int cnt = min(cursor[b], cap);
    const unsigned int* src = coarse + (size_t)b * cap;

    hist[tid] = 0;
    __syncthreads();

    int nIter = (cnt + 255) >> 8;
    for (int i = 0; i < nIter; ++i) {
        int idx = i * 256 + tid;
        if (idx < cnt) atomicAdd(&hist[(src[idx] >> 16) & 255], 1);
    }
    __syncthreads();

    block_excl_scan_256(hist, pstart, wsum, tid);
    cur2[tid] = pstart[tid];
    __syncthreads();

    for (int i = 0; i < nIter; ++i) {
        int idx = i * 256 + tid;
        if (idx < cnt) {
            unsigned int r = src[idx];
            int dl = (r >> 16) & 255;
            int p  = atomicAdd(&cur2[dl], 1);
            sorted[(size_t)b * cap + p] = (unsigned short)(r & 0xFFFFu);
        }
    }

    int node = b * 256 + tid;
    if (node < n) {
        deg[node]       = hist[tid];
        row_start[node] = b * cap + pstart[tid];
    }
}

// ---------------------------------------------------------------------------
// GEMM1 fused with layer-1 gather (R10 barrier-free 256-thr structure).
// Two-phase source-split gather — pass 0 accumulates only src < H,
// pass 1 only src >= H. Each pass's xq working set is 3.2 MB -> fits a
// 4 MB XCD L2, turning ~700cyc L3/HBM latency into ~200cyc L2 hits.
// x A-frag loads + hb stores are non-temporal (via f32x4 ext-vector ptrs —
// HIP float4* is rejected by the builtin) to protect L2 residency.
// ---------------------------------------------------------------------------
__global__ __launch_bounds__(256) void gemm1_fused(
    const unsigned char* __restrict__ xq, const float* __restrict__ x,
    const int* __restrict__ row_start, const int* __restrict__ deg,
    const unsigned short* __restrict__ sorted,
    const unsigned short* __restrict__ W1p, const float* __restrict__ bias,
    unsigned short* __restrict__ hb,
    float* __restrict__ bn_sum, float* __restrict__ bn_sumsq, int n, int H)
{
    __shared__ unsigned short G[64][136];
    __shared__ float red[2][4][128];

    const int block_row = blockIdx.x * 64;
    const int tid  = threadIdx.x;
    const int wave = tid >> 6;
    const int lane = tid & 63;
    const int q    = lane >> 4;
    const int m16  = lane & 15;

    // ---- gather own 16 rows into G: 2 groups of 8 rows, 8 lanes/row ----
    {
        int sub = lane & 7, oct = lane >> 3;
        #pragma unroll
        for (int grp = 0; grp < 2; ++grp) {
            int lr = wave * 16 + grp * 8 + oct;
            int g  = block_row + lr;
            float acc[16];
            #pragma unroll
            for (int j = 0; j < 16; ++j) acc[j] = 0.f;
            int d = 0;
            if (g < n) {
                int base = row_start[g];
                d = deg[g];
                // two passes over the neighbor list, split by source half
                for (int half = 0; half < 2; ++half) {
                    int lo = half ? H : 0;
                    int hi = half ? n : H;
                    int t = 0;
                    for (; t + 8 <= d; t += 8) {
                        uint4 raws[8];
                        #pragma unroll
                        for (int u = 0; u < 8; ++u) {
                            int s = (int)sorted[base + t + u];
                            raws[u] = (uint4){0u,0u,0u,0u};
                            if (s >= lo && s < hi)
                                raws[u] = ((const uint4*)(xq + (size_t)s * DIN))[sub];
                        }
                        #pragma unroll
                        for (int u = 0; u < 8; ++u) {
                            const unsigned int* w = (const unsigned int*)&raws[u];
                            #pragma unroll
                            for (int c = 0; c < 4; ++c) {
                                float o4[4];
                                fp8x4_to_f32(w[c], o4);
                                acc[c*4+0] += o4[0]; acc[c*4+1] += o4[1];
                                acc[c*4+2] += o4[2]; acc[c*4+3] += o4[3];
                            }
                        }
                    }
                    for (; t < d; ++t) {
                        int s = (int)sorted[base + t];
                        if (s >= lo && s < hi) {
                            uint4 raw = ((const uint4*)(xq + (size_t)s * DIN))[sub];
                            const unsigned int* w = (const unsigned int*)&raw;
                            #pragma unroll
                            for (int c = 0; c < 4; ++c) {
                                float o4[4];
                                fp8x4_to_f32(w[c], o4);
                                acc[c*4+0] += o4[0]; acc[c*4+1] += o4[1];
                                acc[c*4+2] += o4[2]; acc[c*4+3] += o4[3];
                            }
                        }
                    }
                }
            }
            float inv = 1.0f / fmaxf((float)d, 1.0f);
            unsigned short t16[16];
            #pragma unroll
            for (int j = 0; j < 16; ++j) t16[j] = f2bf(acc[j] * inv);
            *(uint4*)&G[lr][sub * 16]     = ((uint4*)t16)[0];
            *(uint4*)&G[lr][sub * 16 + 8] = ((uint4*)t16)[1];
        }
    }
    // no __syncthreads: each wave reads only rows it wrote.

    f32x4 acc[8];
    #pragma unroll
    for (int nt = 0; nt < 8; ++nt) acc[nt] = (f32x4){0.f, 0.f, 0.f, 0.f};

    const int grow = block_row + wave * 16 + m16;   // this lane's A row
    #pragma unroll
    for (int ks = 0; ks < 4; ++ks) {
        bf16x8 ag = *(const bf16x8*)&G[wave * 16 + m16][ks * 32 + q * 8];
        const unsigned short* wp0 = W1p + (size_t)ks * 8 * 512;          // Wl1
        #pragma unroll
        for (int nt = 0; nt < 8; ++nt) {
            bf16x8 b = *(const bf16x8*)(wp0 + nt * 512 + lane * 8);
            acc[nt] = __builtin_amdgcn_mfma_f32_16x16x32_bf16(ag, b, acc[nt], 0, 0, 0);
        }
        // X frag direct from fp32 x (non-temporal via ext-vector), regs cvt
        bf16x8 ax;
        {
            f32x4 f0 = {0.f,0.f,0.f,0.f}, f1 = {0.f,0.f,0.f,0.f};
            if (grow < n) {
                const f32x4* xr = (const f32x4*)(x + (size_t)grow * DIN + ks * 32 + q * 8);
                f0 = __builtin_nontemporal_load(xr);
                f1 = __builtin_nontemporal_load(xr + 1);
            }
            unsigned short t[8];
            t[0]=f2bf(f0.x); t[1]=f2bf(f0.y); t[2]=f2bf(f0.z); t[3]=f2bf(f0.w);
            t[4]=f2bf(f1.x); t[5]=f2bf(f1.y); t[6]=f2bf(f1.z); t[7]=f2bf(f1.w);
            ax = *(bf16x8*)t;
        }
        const unsigned short* wp1 = W1p + (size_t)(4 + ks) * 8 * 512;    // Wr1
        #pragma unroll
        for (int nt = 0; nt < 8; ++nt) {
            bf16x8 b = *(const bf16x8*)(wp1 + nt * 512 + lane * 8);
            acc[nt] = __builtin_amdgcn_mfma_f32_16x16x32_bf16(ax, b, acc[nt], 0, 0, 0);
        }
    }

    // ---- epilogue: bias, hb store (non-temporal), BN partials ----
    float psum[8], psq[8];
    #pragma unroll
    for (int nt = 0; nt < 8; ++nt) {
        int col = nt * 16 + m16;
        float bv = bias[col];
        float s = 0.f, ssq = 0.f;
        #pragma unroll
        for (int reg = 0; reg < 4; ++reg) {
            int g = block_row + wave * 16 + q * 4 + reg;
            float v = acc[nt][reg] + bv;
            if (g < n) {
                __builtin_nontemporal_store(f2bf(v), hb + (size_t)g * DH + col);
                s += v; ssq += v * v;
            }
        }
        psum[nt] = s; psq[nt] = ssq;
    }
    #pragma unroll
    for (int nt = 0; nt < 8; ++nt) {
        psum[nt] += __shfl_xor(psum[nt], 16, 64);
        psum[nt] += __shfl_xor(psum[nt], 32, 64);
        psq[nt]  += __shfl_xor(psq[nt], 16, 64);
        psq[nt]  += __shfl_xor(psq[nt], 32, 64);
    }
    if (lane < 16) {
        #pragma unroll
        for (int nt = 0; nt < 8; ++nt) {
            red[0][wave][nt * 16 + lane] = psum[nt];
            red[1][wave][nt * 16 + lane] = psq[nt];
        }
    }
    __syncthreads();
    if (tid < 128) {
        float s = red[0][0][tid] + red[0][1][tid] + red[0][2][tid] + red[0][3][tid];
        float ssq = red[1][0][tid] + red[1][1][tid] + red[1][2][tid] + red[1][3][tid];
        atomicAdd(&bn_sum[tid], s);
        atomicAdd(&bn_sumsq[tid], ssq);
    }
}

// ---------------------------------------------------------------------------
// GEMM2 (MFMA bf16): BN finalize in LDS; A-frags loaded directly from hb and
// BN+ReLU applied in registers. P stored as fp8 e4m3 (3.2 MB -> the layer-2
// gather working set fits a single XCD L2).
// ---------------------------------------------------------------------------
__global__ __launch_bounds__(256) void gemm2p_mfma(
    const unsigned short* __restrict__ hb,
    const float* __restrict__ bn_sum, const float* __restrict__ bn_sumsq,
    const float* __restrict__ gamma, const float* __restrict__ beta,
    const unsigned short* __restrict__ W2p, const float* __restrict__ bias,
    unsigned char* __restrict__ P, float* __restrict__ out, int n)
{
    __shared__ float s_scale[128], s_shift[128];

    const int block_row = blockIdx.x * 64;
    const int tid  = threadIdx.x;
    const int wave = tid >> 6;
    const int lane = tid & 63;
    const int q    = lane >> 4;
    const int m16  = lane & 15;

    if (tid < 128) {
        float invN = 1.0f / (float)n;
        float mu  = bn_sum[tid] * invN;
        float var = bn_sumsq[tid] * invN - mu * mu;
        float sc  = gamma[tid] * rsqrtf(var + BN_EPS);
        s_scale[tid] = sc;
        s_shift[tid] = beta[tid] - mu * sc;
    }
    __syncthreads();

    f32x4 acc[8];
    #pragma unroll
    for (int nt = 0; nt < 8; ++nt) acc[nt] = (f32x4){0.f, 0.f, 0.f, 0.f};

    const int grow = block_row + wave * 16 + m16;
    #pragma unroll
    for (int ks = 0; ks < 4; ++ks) {
        bf16x8 a;
        {
            int kbase = ks * 32 + q * 8;
            float4 sc0 = *(const float4*)&s_scale[kbase];
            float4 sc1 = *(const float4*)&s_scale[kbase + 4];
            float4 sh0 = *(const float4*)&s_shift[kbase];
            float4 sh1 = *(const float4*)&s_shift[kbase + 4];
            unsigned short t[8] = {0,0,0,0,0,0,0,0};
            if (grow < n) {
                uint4 raw = *(const uint4*)(hb + (size_t)grow * DH + kbase);
                const unsigned short* u = (const unsigned short*)&raw;
                t[0] = f2bf(fmaxf(bf2f(u[0]) * sc0.x + sh0.x, 0.f));
                t[1] = f2bf(fmaxf(bf2f(u[1]) * sc0.y + sh0.y, 0.f));
                t[2] = f2bf(fmaxf(bf2f(u[2]) * sc0.z + sh0.z, 0.f));
                t[3] = f2bf(fmaxf(bf2f(u[3]) * sc0.w + sh0.w, 0.f));
                t[4] = f2bf(fmaxf(bf2f(u[4]) * sc1.x + sh1.x, 0.f));
                t[5] = f2bf(fmaxf(bf2f(u[5]) * sc1.y + sh1.y, 0.f));
                t[6] = f2bf(fmaxf(bf2f(u[6]) * sc1.z + sh1.z, 0.f));
                t[7] = f2bf(fmaxf(bf2f(u[7]) * sc1.w + sh1.w, 0.f));
            }
            a = *(bf16x8*)t;
        }
        const unsigned short* wp = W2p + (size_t)ks * 8 * 512;
        #pragma unroll
        for (int nt = 0; nt < 8; ++nt) {
            bf16x8 b = *(const bf16x8*)(wp + nt * 512 + lane * 8);
            acc[nt] = __builtin_amdgcn_mfma_f32_16x16x32_bf16(a, b, acc[nt], 0, 0, 0);
        }
    }

    // P (fp8) for cols 0..63
    #pragma unroll
    for (int nt = 0; nt < 4; ++nt) {
        int col = nt * 16 + m16;
        #pragma unroll
        for (int reg = 0; reg < 4; ++reg) {
            int g = block_row + wave * 16 + q * 4 + reg;
            if (g < n) {
                unsigned int pk = f32x4_to_fp8(acc[nt][reg], 0.f, 0.f, 0.f);
                P[(size_t)g * DOUTC + col] = (unsigned char)(pk & 0xFF);
            }
        }
    }
    // out (fp32, +bias) for cols 64..127
    #pragma unroll
    for (int nt = 4; nt < 8; ++nt) {
        int col = (nt - 4) * 16 + m16;
        float bv = bias[col];
        #pragma unroll
        for (int reg = 0; reg < 4; ++reg) {
            int g = block_row + wave * 16 + q * 4 + reg;
            if (g < n) out[(size_t)g * DOUTC + col] = acc[nt][reg] + bv;
        }
    }
}

// ---------------------------------------------------------------------------
// Layer-2 gather-mean over fp8 P rows (64 B = one cache line), batch-8 MLP.
// 8 rows/wave, 8 lanes/row; each lane owns an 8 B slice (8 fp8 values).
// ---------------------------------------------------------------------------
__global__ __launch_bounds__(256) void agg_gather64_add(
    const int* __restrict__ row_start, const int* __restrict__ deg,
    const unsigned short* __restrict__ sorted, const unsigned char* __restrict__ P,
    float* __restrict__ out, int n)
{
    int wid  = (blockIdx.x * 256 + threadIdx.x) >> 6;
    int lane = threadIdx.x & 63;
    int sub = lane & 7, oct = lane >> 3;
    int r = wid * 8 + oct;
    if (r >= n) return;

    float acc[8];
    #pragma unroll
    for (int j = 0; j < 8; ++j) acc[j] = 0.f;

    int base = row_start[r];
    int d    = deg[r];
    int t = 0;
    for (; t + 8 <= d; t += 8) {
        uint2 raws[8];
        #pragma unroll
        for (int u = 0; u < 8; ++u) {
            int s = (int)sorted[base + t + u];
            raws[u] = ((const uint2*)(P + (size_t)s * DOUTC))[sub];
        }
        #pragma unroll
        for (int u = 0; u < 8; ++u) {
            float o4[4];
            fp8x4_to_f32(raws[u].x, o4);
            acc[0] += o4[0]; acc[1] += o4[1]; acc[2] += o4[2]; acc[3] += o4[3];
            fp8x4_to_f32(raws[u].y, o4);
            acc[4] += o4[0]; acc[5] += o4[1]; acc[6] += o4[2]; acc[7] += o4[3];
        }
    }
    for (; t < d; ++t) {
        int s = (int)sorted[base + t];
        uint2 raw = ((const uint2*)(P + (size_t)s * DOUTC))[sub];
        float o4[4];
        fp8x4_to_f32(raw.x, o4);
        acc[0] += o4[0]; acc[1] += o4[1]; acc[2] += o4[2]; acc[3] += o4[3];
        fp8x4_to_f32(raw.y, o4);
        acc[4] += o4[0]; acc[5] += o4[1]; acc[6] += o4[2]; acc[7] += o4[3];
    }
    float inv = 1.0f / fmaxf((float)d, 1.0f);
    float* op = out + (size_t)r * DOUTC + sub * 8;
    float4 c0 = *(float4*)op;
    float4 c1 = *((float4*)op + 1);
    c0.x += acc[0] * inv; c0.y += acc[1] * inv;
    c0.z += acc[2] * inv; c0.w += acc[3] * inv;
    c1.x += acc[4] * inv; c1.y += acc[5] * inv;
    c1.z += acc[6] * inv; c1.w += acc[7] * inv;
    *(float4*)op = c0;
    *((float4*)op + 1) = c1;
}

// ---------------------------------------------------------------------------
extern "C" void kernel_launch(void* const* d_in, const int* in_sizes, int n_in,
                              void* d_out, int out_size, void* d_ws, size_t ws_size,
                              hipStream_t stream)
{
    const float* x     = (const float*)d_in[0];
    const int*   ei    = (const int*)  d_in[1];
    const float* Wl1   = (const float*)d_in[2];
    const float* Wr1   = (const float*)d_in[3];
    const float* b1    = (const float*)d_in[4];
    const float* gamma = (const float*)d_in[5];
    const float* beta  = (const float*)d_in[6];
    const float* Wl2   = (const float*)d_in[7];
    const float* Wr2   = (const float*)d_in[8];
    const float* b2    = (const float*)d_in[9];
    float*       out   = (float*)d_out;

    const int N = in_sizes[0] / DIN;      // 50000
    const int E = in_sizes[1] / 2;        // 800000

    const int NB  = (N + 255) >> 8;                       // coarse buckets
    int cap = (E / NB) * 3 / 2 + 256;
    cap = (cap + 255) & ~255;

    // workspace layout (segments 16B-aligned)
    float* bn_sum   = (float*)d_ws;                       // 128
    float* bn_sumsq = bn_sum + DH;                        // 128
    int* cursor     = (int*)(bn_sumsq + DH);              // 256
    int* deg        = cursor + 256;                       // N
    int* row_start  = deg + N;                            // N
    unsigned int* coarse   = (unsigned int*)(row_start + N);            // NB*cap
    unsigned short* sorted = (unsigned short*)(coarse + (size_t)NB * cap);
    unsigned short* hb     = sorted + (size_t)NB * cap;   // N*128 bf16
    unsigned short* W1p    = hb + (size_t)N * DH;         // 256*128 bf16
    unsigned short* W2p    = W1p + 256 * 128;             // 128*128 bf16
    unsigned char*  P      = (unsigned char*)(W2p + 128 * 128); // N*64 fp8
    unsigned char*  xq     = P + (size_t)N * DOUTC;       // N*128 fp8

    // zero bn sums + coarse cursors
    hipMemsetAsync(bn_sum, 0, (2 * DH + 256) * sizeof(float), stream);

    dim3 blk(256);
    const int cvtB        = (N * DIN / 8 + 255) / 256;        // 3125
    const int binA_blocks = (E + 4095) / 4096;                // 196
    const int gemm_blocks = (N + 63) / 64;
    const int g64_blocks  = ((N + 7) / 8 + 3) / 4;

    // ---- prep: x-quantize | weight-pack | coarse-bin (one launch) ----
    prep_kernel<<<cvtB + 192 + binA_blocks, blk, 0, stream>>>(
        x, xq, Wl1, Wr1, Wl2, Wr2, W1p, W2p,
        ei, cursor, coarse, N * DIN / 8, cvtB, E, NB, cap);

    // ---- counting sort pass B ----
    bin_fine<<<NB, blk, 0, stream>>>(cursor, coarse, sorted, deg, row_start, N, cap);

    // ---- layer 1: fused gather (src-split) + GEMM + BN partials ----
    gemm1_fused<<<gemm_blocks, blk, 0, stream>>>(xq, x, row_start, deg, sorted,
                                                 W1p, b1, hb, bn_sum, bn_sumsq,
                                                 N, N / 2);

    // ---- layer 2: BN finalize + ReLU + project (P fp8) ----
    gemm2p_mfma<<<gemm_blocks, blk, 0, stream>>>(hb, bn_sum, bn_sumsq,
                                                 gamma, beta, W2p, b2, P, out, N);

    // ---- layer 2 aggregation (fp8 rows, L2-resident) ----
    agg_gather64_add<<<g64_blocks, blk, 0, stream>>>(row_start, deg, sorted,
                                                     P, out, N);
}

// Round 14
// 214.326 us; speedup vs baseline: 1.2151x; 1.2151x over previous
//
#include <hip/hip_runtime.h>
#include <hip/hip_bf16.h>
#include <hip/hip_fp8.h>

#define DIN   128
#define DH    128
#define DOUTC 64
#define BN_EPS 1e-5f

typedef __attribute__((ext_vector_type(8))) short bf16x8;
typedef __attribute__((ext_vector_type(4))) float f32x4;
typedef __attribute__((ext_vector_type(2))) float f32x2;

#ifndef __has_builtin
#define __has_builtin(x) 0
#endif
#if __has_builtin(__builtin_amdgcn_cvt_pk_f32_fp8) && __has_builtin(__builtin_amdgcn_cvt_pk_fp8_f32)
#define HW_FP8 1
#else
#define HW_FP8 0
#endif

__device__ inline unsigned short f2bf(float f) {
    __hip_bfloat16 b = __float2bfloat16(f);
    return *reinterpret_cast<unsigned short*>(&b);
}
__device__ inline float bf2f(unsigned short u) {
    return __uint_as_float(((unsigned int)u) << 16);
}
__device__ inline void fp8x4_to_f32(unsigned int w, float* o) {
#if HW_FP8
    f32x2 lo = __builtin_amdgcn_cvt_pk_f32_fp8((int)w, false);
    f32x2 hi = __builtin_amdgcn_cvt_pk_f32_fp8((int)w, true);
    o[0] = lo.x; o[1] = lo.y; o[2] = hi.x; o[3] = hi.y;
#else
    #pragma unroll
    for (int c = 0; c < 4; ++c) {
        __hip_fp8_e4m3 q; q.__x = (__hip_fp8_storage_t)((w >> (8 * c)) & 0xFF);
        o[c] = (float)q;
    }
#endif
}
__device__ inline unsigned int f32x4_to_fp8(float a, float b, float c, float d) {
#if HW_FP8
    int p = __builtin_amdgcn_cvt_pk_fp8_f32(a, b, 0, false);
    p = __builtin_amdgcn_cvt_pk_fp8_f32(c, d, p, true);
    return (unsigned int)p;
#else
    __hip_fp8_e4m3 qa(a), qb(b), qc(c), qd(d);
    return (unsigned int)qa.__x | ((unsigned int)qb.__x << 8) |
           ((unsigned int)qc.__x << 16) | ((unsigned int)qd.__x << 24);
#endif
}

// ---------------------------------------------------------------------------
// Exclusive prefix scan over 256 LDS ints (all 256 threads must call).
// ---------------------------------------------------------------------------
__device__ inline void block_excl_scan_256(const int* __restrict__ arr,
                                           int* __restrict__ excl,
                                           int* __restrict__ wsum, int tid)
{
    int lane = tid & 63, w = tid >> 6;
    int v = arr[tid];
    int inc = v;
    #pragma unroll
    for (int off = 1; off < 64; off <<= 1) {
        int t = __shfl_up(inc, off, 64);
        if (lane >= off) inc += t;
    }
    if (lane == 63) wsum[w] = inc;
    __syncthreads();
    if (tid == 0) {
        int s = 0;
        #pragma unroll
        for (int i = 0; i < 4; ++i) { int t = wsum[i]; wsum[i] = s; s += t; }
    }
    __syncthreads();
    excl[tid] = inc - v + wsum[w];
    __syncthreads();
}

// ---------------------------------------------------------------------------
// prep_kernel — three independent block ranges:
//   [0, cvtB)              : x -> xq (fp8 e4m3)
//   [cvtB, cvtB+192)       : pack Wl1 / Wr1 / [Wl2|Wr2] into MFMA B-frag order
//   [cvtB+192, ...)        : bin_coarse — counting-sort pass A (dst>>8)
// ---------------------------------------------------------------------------
__global__ __launch_bounds__(256) void prep_kernel(
    const float* __restrict__ x, unsigned char* __restrict__ xq,
    const float* __restrict__ Wl1, const float* __restrict__ Wr1,
    const float* __restrict__ Wl2, const float* __restrict__ Wr2,
    unsigned short* __restrict__ W1p, unsigned short* __restrict__ W2p,
    const int* __restrict__ ei, int* __restrict__ cursor,
    unsigned int* __restrict__ coarse,
    int total8, int cvtB, int E, int nb, int cap)
{
    __shared__ int hist[256], lstart[256], gbase[256], wsum[4];
    __shared__ unsigned int staged[4096];
    const int b = blockIdx.x;
    const int tid = threadIdx.x;

    if (b < cvtB) {
        int i = b * 256 + tid;
        if (i >= total8) return;
        float4 a = ((const float4*)x)[2 * i];
        float4 c = ((const float4*)x)[2 * i + 1];
        uint2 pk;
        pk.x = f32x4_to_fp8(a.x, a.y, a.z, a.w);
        pk.y = f32x4_to_fp8(c.x, c.y, c.z, c.w);
        *(uint2*)(xq + (size_t)i * 8) = pk;
        return;
    }
    if (b < cvtB + 192) {
        int region = (b - cvtB) >> 6;
        int idx = ((b - cvtB) & 63) * 256 + tid;   // 0..16383
        int k = idx >> 7, c = idx & 127;
        int d = ((k >> 5) * 8 + (c >> 4)) * 512 + ((k >> 3) & 3) * 128 + (c & 15) * 8 + (k & 7);
        if (region == 0)      W1p[d] = f2bf(Wl1[idx]);
        else if (region == 1) W1p[128 * 128 + d] = f2bf(Wr1[idx]);
        else {
            float v = (c < 64) ? Wl2[k * 64 + c] : Wr2[k * 64 + (c - 64)];
            W2p[d] = f2bf(v);
        }
        return;
    }

    // ---- bin_coarse ----
    const int chunkBase = (b - cvtB - 192) * 4096;
    hist[tid] = 0;
    __syncthreads();

    unsigned int rec[16]; int pos[16]; int bb[16];
    #pragma unroll
    for (int i = 0; i < 16; ++i) {
        int e = chunkBase + i * 256 + tid;
        if (e < E) {
            int s = ei[e], d = ei[E + e];
            rec[i] = ((unsigned int)d << 16) | (unsigned int)s;
            bb[i]  = d >> 8;
            pos[i] = atomicAdd(&hist[bb[i]], 1);
        } else bb[i] = -1;
    }
    __syncthreads();

    block_excl_scan_256(hist, lstart, wsum, tid);

    if (tid < nb) {
        int c = hist[tid];
        gbase[tid] = c ? atomicAdd(&cursor[tid], c) : 0;
    }
    __syncthreads();

    #pragma unroll
    for (int i = 0; i < 16; ++i)
        if (bb[i] >= 0) staged[lstart[bb[i]] + pos[i]] = rec[i];
    __syncthreads();

    int total = min(4096, E - chunkBase);
    for (int i = tid; i < total; i += 256) {
        unsigned int r = staged[i];
        int bk  = (int)(r >> 24);
        int gp  = gbase[bk] + (i - lstart[bk]);
        if (gp < cap) coarse[(size_t)bk * cap + gp] = r;
    }
}

// ---------------------------------------------------------------------------
// Counting sort pass B: one block per coarse bucket; scatter src (ushort)
// into bucket-owned window; emit deg / row_start.
// ---------------------------------------------------------------------------
__global__ __launch_bounds__(256) void bin_fine(
    const int* __restrict__ cursor, const unsigned int* __restrict__ coarse,
    unsigned short* __restrict__ sorted, int* __restrict__ deg,
    int* __restrict__ row_start, int n, int cap)
{
    __shared__ int hist[256], pstart[256], cur2[256], wsum[4];
    const int b = blockIdx.x, tid = threadIdx.x;
    const int cnt = min(cursor[b], cap);
    const unsigned int* src = coarse + (size_t)b * cap;

    hist[tid] = 0;
    __syncthreads();

    int nIter = (cnt + 255) >> 8;
    for (int i = 0; i < nIter; ++i) {
        int idx = i * 256 + tid;
        if (idx < cnt) atomicAdd(&hist[(src[idx] >> 16) & 255], 1);
    }
    __syncthreads();

    block_excl_scan_256(hist, pstart, wsum, tid);
    cur2[tid] = pstart[tid];
    __syncthreads();

    for (int i = 0; i < nIter; ++i) {
        int idx = i * 256 + tid;
        if (idx < cnt) {
            unsigned int r = src[idx];
            int dl = (r >> 16) & 255;
            int p  = atomicAdd(&cur2[dl], 1);
            sorted[(size_t)b * cap + p] = (unsigned short)(r & 0xFFFFu);
        }
    }

    int node = b * 256 + tid;
    if (node < n) {
        deg[node]       = hist[tid];
        row_start[node] = b * cap + pstart[tid];
    }
}

// ---------------------------------------------------------------------------
// GEMM1 fused with layer-1 gather (R10 structure, batch-4 ILP).
// G-tile: per-row gather-mean of fp8 neighbors; 8 rows/wave x 8 lanes/row,
// 2 sequential groups; single pass, batch-4 index+row loads (R10's batch-8
// cost 32 live VGPRs -> 100 total -> 14.7% occupancy; batch-4 trades half
// the MLP depth for ~2x the resident waves).
// X frags direct from fp32 x (plain loads — R13's non-temporal stores/loads
// doubled WRITE_SIZE and regressed). No barrier between G fill and MFMA.
// ---------------------------------------------------------------------------
__global__ __launch_bounds__(256) void gemm1_fused(
    const unsigned char* __restrict__ xq, const float* __restrict__ x,
    const int* __restrict__ row_start, const int* __restrict__ deg,
    const unsigned short* __restrict__ sorted,
    const unsigned short* __restrict__ W1p, const float* __restrict__ bias,
    unsigned short* __restrict__ hb,
    float* __restrict__ bn_sum, float* __restrict__ bn_sumsq, int n)
{
    __shared__ unsigned short G[64][136];
    __shared__ float red[2][4][128];

    const int block_row = blockIdx.x * 64;
    const int tid  = threadIdx.x;
    const int wave = tid >> 6;
    const int lane = tid & 63;
    const int q    = lane >> 4;
    const int m16  = lane & 15;

    // ---- gather own 16 rows into G: 2 groups of 8 rows, 8 lanes/row ----
    {
        int sub = lane & 7, oct = lane >> 3;
        #pragma unroll
        for (int grp = 0; grp < 2; ++grp) {
            int lr = wave * 16 + grp * 8 + oct;
            int g  = block_row + lr;
            float acc[16];
            #pragma unroll
            for (int j = 0; j < 16; ++j) acc[j] = 0.f;
            int d = 0;
            if (g < n) {
                int base = row_start[g];
                d = deg[g];
                int t = 0;
                for (; t + 4 <= d; t += 4) {
                    uint4 raws[4];
                    #pragma unroll
                    for (int u = 0; u < 4; ++u) {
                        int s = (int)sorted[base + t + u];
                        raws[u] = ((const uint4*)(xq + (size_t)s * DIN))[sub];
                    }
                    #pragma unroll
                    for (int u = 0; u < 4; ++u) {
                        const unsigned int* w = (const unsigned int*)&raws[u];
                        #pragma unroll
                        for (int c = 0; c < 4; ++c) {
                            float o4[4];
                            fp8x4_to_f32(w[c], o4);
                            acc[c*4+0] += o4[0]; acc[c*4+1] += o4[1];
                            acc[c*4+2] += o4[2]; acc[c*4+3] += o4[3];
                        }
                    }
                }
                for (; t < d; ++t) {
                    int s = (int)sorted[base + t];
                    uint4 raw = ((const uint4*)(xq + (size_t)s * DIN))[sub];
                    const unsigned int* w = (const unsigned int*)&raw;
                    #pragma unroll
                    for (int c = 0; c < 4; ++c) {
                        float o4[4];
                        fp8x4_to_f32(w[c], o4);
                        acc[c*4+0] += o4[0]; acc[c*4+1] += o4[1];
                        acc[c*4+2] += o4[2]; acc[c*4+3] += o4[3];
                    }
                }
            }
            float inv = 1.0f / fmaxf((float)d, 1.0f);
            unsigned short t16[16];
            #pragma unroll
            for (int j = 0; j < 16; ++j) t16[j] = f2bf(acc[j] * inv);
            *(uint4*)&G[lr][sub * 16]     = ((uint4*)t16)[0];
            *(uint4*)&G[lr][sub * 16 + 8] = ((uint4*)t16)[1];
        }
    }
    // no __syncthreads: each wave reads only rows it wrote.

    f32x4 acc[8];
    #pragma unroll
    for (int nt = 0; nt < 8; ++nt) acc[nt] = (f32x4){0.f, 0.f, 0.f, 0.f};

    const int grow = block_row + wave * 16 + m16;   // this lane's A row
    #pragma unroll
    for (int ks = 0; ks < 4; ++ks) {
        bf16x8 ag = *(const bf16x8*)&G[wave * 16 + m16][ks * 32 + q * 8];
        const unsigned short* wp0 = W1p + (size_t)ks * 8 * 512;          // Wl1
        #pragma unroll
        for (int nt = 0; nt < 8; ++nt) {
            bf16x8 b = *(const bf16x8*)(wp0 + nt * 512 + lane * 8);
            acc[nt] = __builtin_amdgcn_mfma_f32_16x16x32_bf16(ag, b, acc[nt], 0, 0, 0);
        }
        // X frag direct from fp32 x, converted in regs
        bf16x8 ax;
        {
            float4 f0 = {0.f,0.f,0.f,0.f}, f1 = {0.f,0.f,0.f,0.f};
            if (grow < n) {
                const float* xr = x + (size_t)grow * DIN + ks * 32 + q * 8;
                f0 = *(const float4*)xr;
                f1 = *(const float4*)(xr + 4);
            }
            unsigned short t[8];
            t[0]=f2bf(f0.x); t[1]=f2bf(f0.y); t[2]=f2bf(f0.z); t[3]=f2bf(f0.w);
            t[4]=f2bf(f1.x); t[5]=f2bf(f1.y); t[6]=f2bf(f1.z); t[7]=f2bf(f1.w);
            ax = *(bf16x8*)t;
        }
        const unsigned short* wp1 = W1p + (size_t)(4 + ks) * 8 * 512;    // Wr1
        #pragma unroll
        for (int nt = 0; nt < 8; ++nt) {
            bf16x8 b = *(const bf16x8*)(wp1 + nt * 512 + lane * 8);
            acc[nt] = __builtin_amdgcn_mfma_f32_16x16x32_bf16(ax, b, acc[nt], 0, 0, 0);
        }
    }

    // ---- epilogue: bias, hb store, BN partials ----
    float psum[8], psq[8];
    #pragma unroll
    for (int nt = 0; nt < 8; ++nt) {
        int col = nt * 16 + m16;
        float bv = bias[col];
        float s = 0.f, ssq = 0.f;
        #pragma unroll
        for (int reg = 0; reg < 4; ++reg) {
            int g = block_row + wave * 16 + q * 4 + reg;
            float v = acc[nt][reg] + bv;
            if (g < n) {
                hb[(size_t)g * DH + col] = f2bf(v);
                s += v; ssq += v * v;
            }
        }
        psum[nt] = s; psq[nt] = ssq;
    }
    #pragma unroll
    for (int nt = 0; nt < 8; ++nt) {
        psum[nt] += __shfl_xor(psum[nt], 16, 64);
        psum[nt] += __shfl_xor(psum[nt], 32, 64);
        psq[nt]  += __shfl_xor(psq[nt], 16, 64);
        psq[nt]  += __shfl_xor(psq[nt], 32, 64);
    }
    if (lane < 16) {
        #pragma unroll
        for (int nt = 0; nt < 8; ++nt) {
            red[0][wave][nt * 16 + lane] = psum[nt];
            red[1][wave][nt * 16 + lane] = psq[nt];
        }
    }
    __syncthreads();
    if (tid < 128) {
        float s = red[0][0][tid] + red[0][1][tid] + red[0][2][tid] + red[0][3][tid];
        float ssq = red[1][0][tid] + red[1][1][tid] + red[1][2][tid] + red[1][3][tid];
        atomicAdd(&bn_sum[tid], s);
        atomicAdd(&bn_sumsq[tid], ssq);
    }
}

// ---------------------------------------------------------------------------
// GEMM2 (MFMA bf16): BN finalize in LDS; A-frags loaded directly from hb and
// BN+ReLU applied in registers. P stored as fp8 e4m3 (halves layer-2 gather
// bytes; validated numerically in R13: absmax 0.0352 < 0.0469).
// ---------------------------------------------------------------------------
__global__ __launch_bounds__(256) void gemm2p_mfma(
    const unsigned short* __restrict__ hb,
    const float* __restrict__ bn_sum, const float* __restrict__ bn_sumsq,
    const float* __restrict__ gamma, const float* __restrict__ beta,
    const unsigned short* __restrict__ W2p, const float* __restrict__ bias,
    unsigned char* __restrict__ P, float* __restrict__ out, int n)
{
    __shared__ float s_scale[128], s_shift[128];

    const int block_row = blockIdx.x * 64;
    const int tid  = threadIdx.x;
    const int wave = tid >> 6;
    const int lane = tid & 63;
    const int q    = lane >> 4;
    const int m16  = lane & 15;

    if (tid < 128) {
        float invN = 1.0f / (float)n;
        float mu  = bn_sum[tid] * invN;
        float var = bn_sumsq[tid] * invN - mu * mu;
        float sc  = gamma[tid] * rsqrtf(var + BN_EPS);
        s_scale[tid] = sc;
        s_shift[tid] = beta[tid] - mu * sc;
    }
    __syncthreads();

    f32x4 acc[8];
    #pragma unroll
    for (int nt = 0; nt < 8; ++nt) acc[nt] = (f32x4){0.f, 0.f, 0.f, 0.f};

    const int grow = block_row + wave * 16 + m16;
    #pragma unroll
    for (int ks = 0; ks < 4; ++ks) {
        bf16x8 a;
        {
            int kbase = ks * 32 + q * 8;
            float4 sc0 = *(const float4*)&s_scale[kbase];
            float4 sc1 = *(const float4*)&s_scale[kbase + 4];
            float4 sh0 = *(const float4*)&s_shift[kbase];
            float4 sh1 = *(const float4*)&s_shift[kbase + 4];
            unsigned short t[8] = {0,0,0,0,0,0,0,0};
            if (grow < n) {
                uint4 raw = *(const uint4*)(hb + (size_t)grow * DH + kbase);
                const unsigned short* u = (const unsigned short*)&raw;
                t[0] = f2bf(fmaxf(bf2f(u[0]) * sc0.x + sh0.x, 0.f));
                t[1] = f2bf(fmaxf(bf2f(u[1]) * sc0.y + sh0.y, 0.f));
                t[2] = f2bf(fmaxf(bf2f(u[2]) * sc0.z + sh0.z, 0.f));
                t[3] = f2bf(fmaxf(bf2f(u[3]) * sc0.w + sh0.w, 0.f));
                t[4] = f2bf(fmaxf(bf2f(u[4]) * sc1.x + sh1.x, 0.f));
                t[5] = f2bf(fmaxf(bf2f(u[5]) * sc1.y + sh1.y, 0.f));
                t[6] = f2bf(fmaxf(bf2f(u[6]) * sc1.z + sh1.z, 0.f));
                t[7] = f2bf(fmaxf(bf2f(u[7]) * sc1.w + sh1.w, 0.f));
            }
            a = *(bf16x8*)t;
        }
        const unsigned short* wp = W2p + (size_t)ks * 8 * 512;
        #pragma unroll
        for (int nt = 0; nt < 8; ++nt) {
            bf16x8 b = *(const bf16x8*)(wp + nt * 512 + lane * 8);
            acc[nt] = __builtin_amdgcn_mfma_f32_16x16x32_bf16(a, b, acc[nt], 0, 0, 0);
        }
    }

    // P (fp8) for cols 0..63
    #pragma unroll
    for (int nt = 0; nt < 4; ++nt) {
        int col = nt * 16 + m16;
        #pragma unroll
        for (int reg = 0; reg < 4; ++reg) {
            int g = block_row + wave * 16 + q * 4 + reg;
            if (g < n) {
                unsigned int pk = f32x4_to_fp8(acc[nt][reg], 0.f, 0.f, 0.f);
                P[(size_t)g * DOUTC + col] = (unsigned char)(pk & 0xFF);
            }
        }
    }
    // out (fp32, +bias) for cols 64..127
    #pragma unroll
    for (int nt = 4; nt < 8; ++nt) {
        int col = (nt - 4) * 16 + m16;
        float bv = bias[col];
        #pragma unroll
        for (int reg = 0; reg < 4; ++reg) {
            int g = block_row + wave * 16 + q * 4 + reg;
            if (g < n) out[(size_t)g * DOUTC + col] = acc[nt][reg] + bv;
        }
    }
}

// ---------------------------------------------------------------------------
// Layer-2 gather-mean over fp8 P rows (64 B = one cache line), batch-8 MLP
// (uint2 regs — half the VGPR cost of the bf16 version).
// 8 rows/wave, 8 lanes/row; each lane owns an 8 B slice (8 fp8 values).
// ---------------------------------------------------------------------------
__global__ __launch_bounds__(256) void agg_gather64_add(
    const int* __restrict__ row_start, const int* __restrict__ deg,
    const unsigned short* __restrict__ sorted, const unsigned char* __restrict__ P,
    float* __restrict__ out, int n)
{
    int wid  = (blockIdx.x * 256 + threadIdx.x) >> 6;
    int lane = threadIdx.x & 63;
    int sub = lane & 7, oct = lane >> 3;
    int r = wid * 8 + oct;
    if (r >= n) return;

    float acc[8];
    #pragma unroll
    for (int j = 0; j < 8; ++j) acc[j] = 0.f;

    int base = row_start[r];
    int d    = deg[r];
    int t = 0;
    for (; t + 8 <= d; t += 8) {
        uint2 raws[8];
        #pragma unroll
        for (int u = 0; u < 8; ++u) {
            int s = (int)sorted[base + t + u];
            raws[u] = ((const uint2*)(P + (size_t)s * DOUTC))[sub];
        }
        #pragma unroll
        for (int u = 0; u < 8; ++u) {
            float o4[4];
            fp8x4_to_f32(raws[u].x, o4);
            acc[0] += o4[0]; acc[1] += o4[1]; acc[2] += o4[2]; acc[3] += o4[3];
            fp8x4_to_f32(raws[u].y, o4);
            acc[4] += o4[0]; acc[5] += o4[1]; acc[6] += o4[2]; acc[7] += o4[3];
        }
    }
    for (; t < d; ++t) {
        int s = (int)sorted[base + t];
        uint2 raw = ((const uint2*)(P + (size_t)s * DOUTC))[sub];
        float o4[4];
        fp8x4_to_f32(raw.x, o4);
        acc[0] += o4[0]; acc[1] += o4[1]; acc[2] += o4[2]; acc[3] += o4[3];
        fp8x4_to_f32(raw.y, o4);
        acc[4] += o4[0]; acc[5] += o4[1]; acc[6] += o4[2]; acc[7] += o4[3];
    }
    float inv = 1.0f / fmaxf((float)d, 1.0f);
    float* op = out + (size_t)r * DOUTC + sub * 8;
    float4 c0 = *(float4*)op;
    float4 c1 = *((float4*)op + 1);
    c0.x += acc[0] * inv; c0.y += acc[1] * inv;
    c0.z += acc[2] * inv; c0.w += acc[3] * inv;
    c1.x += acc[4] * inv; c1.y += acc[5] * inv;
    c1.z += acc[6] * inv; c1.w += acc[7] * inv;
    *(float4*)op = c0;
    *((float4*)op + 1) = c1;
}

// ---------------------------------------------------------------------------
extern "C" void kernel_launch(void* const* d_in, const int* in_sizes, int n_in,
                              void* d_out, int out_size, void* d_ws, size_t ws_size,
                              hipStream_t stream)
{
    const float* x     = (const float*)d_in[0];
    const int*   ei    = (const int*)  d_in[1];
    const float* Wl1   = (const float*)d_in[2];
    const float* Wr1   = (const float*)d_in[3];
    const float* b1    = (const float*)d_in[4];
    const float* gamma = (const float*)d_in[5];
    const float* beta  = (const float*)d_in[6];
    const float* Wl2   = (const float*)d_in[7];
    const float* Wr2   = (const float*)d_in[8];
    const float* b2    = (const float*)d_in[9];
    float*       out   = (float*)d_out;

    const int N = in_sizes[0] / DIN;      // 50000
    const int E = in_sizes[1] / 2;        // 800000

    const int NB  = (N + 255) >> 8;                       // coarse buckets
    int cap = (E / NB) * 3 / 2 + 256;
    cap = (cap + 255) & ~255;

    // workspace layout (segments 16B-aligned)
    float* bn_sum   = (float*)d_ws;                       // 128
    float* bn_sumsq = bn_sum + DH;                        // 128
    int* cursor     = (int*)(bn_sumsq + DH);              // 256
    int* deg        = cursor + 256;                       // N
    int* row_start  = deg + N;                            // N
    unsigned int* coarse   = (unsigned int*)(row_start + N);            // NB*cap
    unsigned short* sorted = (unsigned short*)(coarse + (size_t)NB * cap);
    unsigned short* hb     = sorted + (size_t)NB * cap;   // N*128 bf16
    unsigned short* W1p    = hb + (size_t)N * DH;         // 256*128 bf16
    unsigned short* W2p    = W1p + 256 * 128;             // 128*128 bf16
    unsigned char*  P      = (unsigned char*)(W2p + 128 * 128); // N*64 fp8
    unsigned char*  xq     = P + (size_t)N * DOUTC;       // N*128 fp8

    // zero bn sums + coarse cursors
    hipMemsetAsync(bn_sum, 0, (2 * DH + 256) * sizeof(float), stream);

    dim3 blk(256);
    const int cvtB        = (N * DIN / 8 + 255) / 256;        // 3125
    const int binA_blocks = (E + 4095) / 4096;                // 196
    const int gemm_blocks = (N + 63) / 64;
    const int g64_blocks  = ((N + 7) / 8 + 3) / 4;

    // ---- prep: x-quantize | weight-pack | coarse-bin (one launch) ----
    prep_kernel<<<cvtB + 192 + binA_blocks, blk, 0, stream>>>(
        x, xq, Wl1, Wr1, Wl2, Wr2, W1p, W2p,
        ei, cursor, coarse, N * DIN / 8, cvtB, E, NB, cap);

    // ---- counting sort pass B ----
    bin_fine<<<NB, blk, 0, stream>>>(cursor, coarse, sorted, deg, row_start, N, cap);

    // ---- layer 1: fused gather + GEMM + BN partials ----
    gemm1_fused<<<gemm_blocks, blk, 0, stream>>>(xq, x, row_start, deg, sorted,
                                                 W1p, b1, hb, bn_sum, bn_sumsq, N);

    // ---- layer 2: BN finalize + ReLU + project (P fp8) ----
    gemm2p_mfma<<<gemm_blocks, blk, 0, stream>>>(hb, bn_sum, bn_sumsq,
                                                 gamma, beta, W2p, b2, P, out, N);

    // ---- layer 2 aggregation (fp8 rows, L2-resident) ----
    agg_gather64_add<<<g64_blocks, blk, 0, stream>>>(row_start, deg, sorted,
                                                     P, out, N);
}